// Round 13
// baseline (5216.219 us; speedup 1.0000x reference)
//
#include <hip/hip_runtime.h>
#include <math.h>

typedef unsigned short u16;
typedef unsigned int   u32;
typedef unsigned long long u64;
typedef __bf16 bf16x8 __attribute__((ext_vector_type(8)));
typedef float  f32x4  __attribute__((ext_vector_type(4)));

#define BB 256
#define TT 256
#define HD 256
#define ED 128
#define NSTEPS 265

/* ws layout (u32 units):
   [0, H_U32)        : h ping-pong, packed bf16 hi|lo<<16  [10][2][256][256]
   [CTR_OFF, +512)   : 8 barrier counters (128B padded) + gen broadcast @+256
   [XP_OFF, +XP_U32) : packed x  [256][256][8]
   [WT_OFF, ...)     : fragment-ordered bf16 weights (8j blocks, 4 streams) */
#define H_U32   (10 * 2 * BB * HD)
#define CTR_OFF H_U32
#define CTR_U32 512
#define XP_OFF  (H_U32 + CTR_U32)
#define XP_U32  (BB * TT * 8)
#define WT_OFF  (XP_OFF + XP_U32)

__constant__ size_t g_woff[10] = {0ul,589824ul,1638400ul,2686976ul,3735552ul,
                                  4784128ul,5177344ul,5439488ul,5701632ul,5963776ul};
__constant__ int g_cb[11] = {0,73728,204800,335872,466944,598016,
                             647168,679936,712704,745472,778240};

__device__ __forceinline__ u16 f2bf_hi(float f) {
    u32 u = __float_as_uint(f);
    u32 r = (u + 0x7FFFu + ((u >> 16) & 1u)) >> 16;
    return (u16)r;
}
__device__ __forceinline__ float bf2f(u16 h) { return __uint_as_float(((u32)h) << 16); }
__device__ __forceinline__ float sigmoidf_(float v) { return 1.0f / (1.0f + expf(-v)); }

__global__ __launch_bounds__(256) void zero_state(u32* wsd) {
    const int n = XP_OFF;
    for (int i = blockIdx.x * blockDim.x + threadIdx.x; i < n; i += gridDim.x * blockDim.x)
        wsd[i] = 0u;
}

__global__ __launch_bounds__(256) void conv_x(const float* __restrict__ x, u32* __restrict__ wsd) {
    u32* xp = wsd + XP_OFF;
    for (int i = blockIdx.x * blockDim.x + threadIdx.x; i < XP_U32; i += gridDim.x * blockDim.x) {
        float v = x[i];
        u16 hi = f2bf_hi(v);
        u16 lo = f2bf_hi(v - bf2f(hi));
        xp[i] = (u32)hi | ((u32)lo << 16);
    }
}

/* weights -> bf16 hi/lo, 16x16x32 fragment order, 8-j blocks:
   chunk = (((jt*4 + mt*2 + p)*nk) + kt)*64 + lane
   r15=lane&15: jloc=r15>>1, gp=r15&1; gate = mt*2+gp; j = jt*8 + jloc;
   W row = gate*hd + j ; k = kt*32 + (lane>>4)*8 + e                        */
__global__ __launch_bounds__(256) void conv_all(
    const float* __restrict__ w_ih0_1, const float* __restrict__ w_ihr_1,
    const float* __restrict__ w_hh_1,
    const float* __restrict__ w_ih0_2, const float* __restrict__ w_ihr_2,
    const float* __restrict__ w_hh_2,
    u32* __restrict__ wsd)
{
    __bf16* dst0 = (__bf16*)(wsd + WT_OFF);
    const int nch = 778240;
    for (int ci = blockIdx.x * blockDim.x + threadIdx.x; ci < nch;
         ci += gridDim.x * blockDim.x) {
        int l = 0;
        while (ci >= g_cb[l + 1]) ++l;
        int di = ci - g_cb[l];

        const int hd  = (l < 5) ? 256 : 128;
        const int din = (l == 0) ? 32 : ((l < 6) ? 256 : 128);
        const int xw  = (l == 0) ? 8 : din;
        const int Kp  = din + hd;
        const int nk  = Kp >> 5;

        const float *wih, *whh; int wihld, whhld;
        if (l == 0)      { wih = w_ih0_1;                                whh = w_hh_1;
                           wihld = 8;   whhld = 256; }
        else if (l < 5)  { wih = w_ihr_1 + (size_t)(l - 1) * 1024 * 256; whh = w_hh_1 + (size_t)l * 1024 * 256;
                           wihld = 256; whhld = 256; }
        else if (l == 5) { wih = w_ih0_2;                                whh = w_hh_2;
                           wihld = 256; whhld = 128; }
        else             { wih = w_ihr_2 + (size_t)(l - 6) * 512 * 128;  whh = w_hh_2 + (size_t)(l - 5) * 512 * 128;
                           wihld = 128; whhld = 128; }

        int lane = di & 63;
        int rem  = di >> 6;
        int kt   = rem % nk;
        int rem2 = rem / nk;
        int p    = rem2 & 1;
        int mt   = (rem2 >> 1) & 1;
        int jt   = rem2 >> 2;
        int r15  = lane & 15, kqc = lane >> 4;
        int jloc = r15 >> 1, gp = r15 & 1;
        int row  = (mt * 2 + gp) * hd + jt * 8 + jloc;

        bf16x8 o8;
        #pragma unroll
        for (int e = 0; e < 8; ++e) {
            int k = kt * 32 + kqc * 8 + e;
            float v = 0.0f;
            if (k < xw) v = wih[(size_t)row * wihld + k];
            else if (k >= din && k < Kp) v = whh[(size_t)row * whhld + (k - din)];
            __bf16 h = (__bf16)v;
            o8[e] = p ? (__bf16)(v - (float)h) : h;
        }
        *(bf16x8*)(dst0 + g_woff[l] + (size_t)di * 8) = o8;
    }
}

__device__ __forceinline__ void unpack8(const uint4& a, const uint4& b, bf16x8& bh, bf16x8& bl) {
    union { u32 u[4]; bf16x8 v; } H, L;
    H.u[0] = (a.x & 0xFFFFu) | (a.y << 16);
    H.u[1] = (a.z & 0xFFFFu) | (a.w << 16);
    H.u[2] = (b.x & 0xFFFFu) | (b.y << 16);
    H.u[3] = (b.z & 0xFFFFu) | (b.w << 16);
    L.u[0] = (a.x >> 16) | (a.y & 0xFFFF0000u);
    L.u[1] = (a.z >> 16) | (a.w & 0xFFFF0000u);
    L.u[2] = (b.x >> 16) | (b.y & 0xFFFF0000u);
    L.u[3] = (b.z >> 16) | (b.w & 0xFFFF0000u);
    bh = H.v; bl = L.v;
}

/* persistent step loop; wave = 8 j x 4 gates (2 M-tiles: {i,f},{g,o}) x 16 b */
template<int NKI, int NKT, bool ISL0>
__device__ void run_persist(int l, int bid, int xcd, int jt, int bt, int hd, u32 arr7,
    const float* __restrict__ bias, u32* __restrict__ hbuf, u32* __restrict__ ctr,
    const u32* __restrict__ xp, float* __restrict__ out, const u16* __restrict__ A_sh)
{
    constexpr int DIN = NKI * 32;
    constexpr int RS  = (NKT < 4) ? NKT : 4;

    const int tid  = threadIdx.x;
    const int lane = tid & 63;
    const int wv   = tid >> 6;
    const int r15  = lane & 15;
    const int kqc  = lane >> 4;
    const int brow = bt * 128 + wv * 16 + r15;
    const int jA   = jt * 8 + kqc * 2;           /* lane's j pair: jA, jA+1 */

    const int t0h = (0 * NKT) * 512 + lane * 8;
    const int t0l = (1 * NKT) * 512 + lane * 8;
    const int t1h = (2 * NKT) * 512 + lane * 8;
    const int t1l = (3 * NKT) * 512 + lane * 8;

    float2 bI = *(const float2*)&bias[0 * hd + jA];
    float2 bF = *(const float2*)&bias[1 * hd + jA];
    float2 bG = *(const float2*)&bias[2 * hd + jA];
    float2 bO = *(const float2*)&bias[3 * hd + jA];

    float cA = 0.f, cB = 0.f;
    const int lm = (l > 0) ? (l - 1) : 0;

    for (int w = 0; w < NSTEPS; ++w) {
        const int t = w - l;
        if (t >= 0 && t < TT) {
            const u32* hin   = hbuf + ((size_t)lm * 2 + (t & 1)) * (BB * HD);
            const u32* hprev = hbuf + ((size_t)l * 2 + ((t & 1) ^ 1)) * (BB * HD);
            u32*       hout  = hbuf + ((size_t)l * 2 + (t & 1)) * (BB * HD);

            auto ldB = [&](int kt, uint4& A, uint4& B) {
                if constexpr (ISL0) {
                    if (kt == 0) {
                        if (kqc == 0) {
                            const uint4* p = (const uint4*)(xp + ((size_t)brow * TT + t) * 8);
                            A = p[0]; B = p[1];
                        } else { A = make_uint4(0,0,0,0); B = make_uint4(0,0,0,0); }
                    } else {
                        const u32* p = hprev + (size_t)brow * HD + (kt * 32 - 32) + kqc * 8;
                        A = *(const uint4*)p; B = *(const uint4*)(p + 4);
                    }
                } else {
                    const int k0 = kt * 32 + kqc * 8;
                    const u32* p = (k0 < DIN) ? (hin + (size_t)brow * HD + k0)
                                              : (hprev + (size_t)brow * HD + (k0 - DIN));
                    A = *(const uint4*)p; B = *(const uint4*)(p + 4);
                }
            };

            f32x4 acc0 = {0.f,0.f,0.f,0.f};   /* M-tile 0: gates i,f */
            f32x4 acc1 = {0.f,0.f,0.f,0.f};   /* M-tile 1: gates g,o */

            uint4 ra[RS], rb[RS];
            #pragma unroll
            for (int i = 0; i < RS; ++i) ldB(i, ra[i], rb[i]);

            #pragma unroll
            for (int kt = 0; kt < NKT; ++kt) {
                bf16x8 bh, bl;
                unpack8(ra[kt % RS], rb[kt % RS], bh, bl);
                if (kt + RS < NKT) ldB(kt + RS, ra[kt % RS], rb[kt % RS]);

                const int kof = kt * 512;
                bf16x8 a0h = *(const bf16x8*)&A_sh[t0h + kof];
                bf16x8 a0l = *(const bf16x8*)&A_sh[t0l + kof];
                bf16x8 a1h = *(const bf16x8*)&A_sh[t1h + kof];
                bf16x8 a1l = *(const bf16x8*)&A_sh[t1l + kof];

                acc0 = __builtin_amdgcn_mfma_f32_16x16x32_bf16(a0h, bh, acc0, 0, 0, 0);
                acc1 = __builtin_amdgcn_mfma_f32_16x16x32_bf16(a1h, bh, acc1, 0, 0, 0);
                acc0 = __builtin_amdgcn_mfma_f32_16x16x32_bf16(a0h, bl, acc0, 0, 0, 0);
                acc1 = __builtin_amdgcn_mfma_f32_16x16x32_bf16(a1h, bl, acc1, 0, 0, 0);
                acc0 = __builtin_amdgcn_mfma_f32_16x16x32_bf16(a0l, bh, acc0, 0, 0, 0);
                acc1 = __builtin_amdgcn_mfma_f32_16x16x32_bf16(a1l, bh, acc1, 0, 0, 0);
            }

            /* epilogue: lane = batch brow, j pair (jA, jA+1), all 4 gates:
               acc0 = {i(jA), f(jA), i(jB), f(jB)}, acc1 = {g(jA), o(jA), g(jB), o(jB)} */
            float hA, hB;
            {
                float i_, f_, g_, o_;
                i_ = sigmoidf_(acc0[0] + bI.x); f_ = sigmoidf_(acc0[1] + bF.x);
                g_ = tanhf   (acc1[0] + bG.x); o_ = sigmoidf_(acc1[1] + bO.x);
                cA = fmaf(f_, cA, i_ * g_); hA = o_ * tanhf(cA);
                i_ = sigmoidf_(acc0[2] + bI.y); f_ = sigmoidf_(acc0[3] + bF.y);
                g_ = tanhf   (acc1[2] + bG.y); o_ = sigmoidf_(acc1[3] + bO.y);
                cB = fmaf(f_, cB, i_ * g_); hB = o_ * tanhf(cB);
            }

            u32 pkA, pkB;
            {
                u16 h0 = f2bf_hi(hA); pkA = (u32)h0 | ((u32)f2bf_hi(hA - bf2f(h0)) << 16);
                u16 h1 = f2bf_hi(hB); pkB = (u32)h1 | ((u32)f2bf_hi(hB - bf2f(h1)) << 16);
            }
            __hip_atomic_store((u64*)(hout + (size_t)brow * HD + jA),
                               (u64)pkA | ((u64)pkB << 32),
                               __ATOMIC_RELAXED, __HIP_MEMORY_SCOPE_AGENT);

            if (l == 9 && t == TT - 1)
                *(float2*)&out[(size_t)brow * ED + jA] = make_float2(hA, hB);
        }

        /* ---- global barrier: per-XCD arrivals; block 0 aggregates and
           broadcasts a generation word; everyone polls one word ---- */
        __syncthreads();
        if (tid == 0) {
            __hip_atomic_fetch_add(&ctr[xcd * 32], 1u,
                                   __ATOMIC_RELAXED, __HIP_MEMORY_SCOPE_AGENT);
            const u32 w1 = (u32)(w + 1);
            if (bid == 0) {
                for (int it = 0; it < (1 << 22); ++it) {
                    bool ok = true;
                    #pragma unroll
                    for (int r = 0; r < 8; ++r) {
                        u32 tgt = ((r == 7) ? arr7 : 64u) * w1;
                        ok &= (__hip_atomic_load(&ctr[r * 32], __ATOMIC_RELAXED,
                                                 __HIP_MEMORY_SCOPE_AGENT) >= tgt);
                    }
                    if (ok) break;
                    __builtin_amdgcn_s_sleep(1);
                }
                __hip_atomic_store(&ctr[256], w1, __ATOMIC_RELAXED, __HIP_MEMORY_SCOPE_AGENT);
            } else {
                for (int it = 0; it < (1 << 22); ++it) {
                    if (__hip_atomic_load(&ctr[256], __ATOMIC_RELAXED,
                                          __HIP_MEMORY_SCOPE_AGENT) >= w1) break;
                    __builtin_amdgcn_s_sleep(1);
                }
            }
            __builtin_amdgcn_fence(__ATOMIC_ACQUIRE, "agent");  /* inv, no writeback */
        }
        __syncthreads();
    }
}

/* Grid 512 (480 active), 512 thr = 8 waves x 16 batches, 8-j blocks, 64KB LDS
   -> 2 blocks/CU, 4 waves/SIMD.  bid%8 = XCD; each (layer,bt) sharing group
   of 32 (stack1) / 16 (stack2) jt-blocks lives on one XCD:
     xcd0: l0b0 | l5b0 | l6b0      xcd1: l0b1 | l5b1 | l6b1
     xcd2: l1b0 | l7b0 | l8b0      xcd3: l1b1 | l7b1 | l8b1
     xcd4: l2b0 | l9b0 | l9b1      xcd5: l2b1 | l3b0
     xcd6: l3b1 | l4b0             xcd7: l4b1 | (32 idle)                   */
__global__ __launch_bounds__(512, 4) void lstm_persist(
    const float* __restrict__ b_1, const float* __restrict__ b_2,
    u32* __restrict__ wsd, float* __restrict__ out)
{
    __shared__ __align__(16) u16 A_sh[32768];   /* 64 KiB */

    const int bid = blockIdx.x;
    const int xcd = bid & 7, slot = bid >> 3;
    int l, jt, bt;
    if (xcd < 2)       { bt = xcd;
                         if (slot < 32)      { l = 0; jt = slot; }
                         else if (slot < 48) { l = 5; jt = slot - 32; }
                         else                { l = 6; jt = slot - 48; } }
    else if (xcd < 4)  { bt = xcd - 2;
                         if (slot < 32)      { l = 1; jt = slot; }
                         else if (slot < 48) { l = 7; jt = slot - 32; }
                         else                { l = 8; jt = slot - 48; } }
    else if (xcd == 4) { if (slot < 32)      { l = 2; bt = 0; jt = slot; }
                         else if (slot < 48) { l = 9; bt = 0; jt = slot - 32; }
                         else                { l = 9; bt = 1; jt = slot - 48; } }
    else if (xcd == 5) { if (slot < 32)      { l = 2; bt = 1; jt = slot; }
                         else                { l = 3; bt = 0; jt = slot - 32; } }
    else if (xcd == 6) { if (slot < 32)      { l = 3; bt = 1; jt = slot; }
                         else                { l = 4; bt = 0; jt = slot - 32; } }
    else               { if (slot >= 32) return; l = 4; bt = 1; jt = slot; }

    const int hd  = (l < 5) ? 256 : 128;
    const int din = (l == 0) ? 32 : ((l < 6) ? 256 : 128);
    const int nk  = (din + hd) >> 5;
    const float* bias = (l < 5) ? (b_1 + l * 1024) : (b_2 + (l - 5) * 512);

    u32* hbuf = wsd;
    u32* ctr  = wsd + CTR_OFF;
    const u32* xp = wsd + XP_OFF;
    const u16* wt = (const u16*)(wsd + WT_OFF);

    /* one-time: copy this block's 4-stream fragment slice into LDS */
    {
        const uint4* src = (const uint4*)(wt + g_woff[l] + (size_t)jt * 4 * nk * 512);
        uint4* dst = (uint4*)A_sh;
        const int n4 = nk * 256;
        for (int i = threadIdx.x; i < n4; i += 512) dst[i] = src[i];
    }
    __syncthreads();

    if (l == 0)
        run_persist<1, 9, true >(l, bid, xcd, jt, bt, hd, 32u, bias, hbuf, ctr, xp, out, A_sh);
    else if (l < 5)
        run_persist<8, 16, false>(l, bid, xcd, jt, bt, hd, 32u, bias, hbuf, ctr, xp, out, A_sh);
    else if (l == 5)
        run_persist<8, 12, false>(l, bid, xcd, jt, bt, hd, 32u, bias, hbuf, ctr, xp, out, A_sh);
    else
        run_persist<4, 8, false>(l, bid, xcd, jt, bt, hd, 32u, bias, hbuf, ctr, xp, out, A_sh);
}

extern "C" void kernel_launch(void* const* d_in, const int* in_sizes, int n_in,
                              void* d_out, int out_size, void* d_ws, size_t ws_size,
                              hipStream_t stream) {
    const float* x       = (const float*)d_in[0];
    const float* w_ih0_1 = (const float*)d_in[1];
    const float* w_ihr_1 = (const float*)d_in[2];
    const float* w_hh_1  = (const float*)d_in[3];
    const float* b_1     = (const float*)d_in[4];
    const float* w_ih0_2 = (const float*)d_in[5];
    const float* w_ihr_2 = (const float*)d_in[6];
    const float* w_hh_2  = (const float*)d_in[7];
    const float* b_2     = (const float*)d_in[8];
    u32*   wsd = (u32*)d_ws;
    float* out = (float*)d_out;

    hipLaunchKernelGGL(zero_state, dim3(1024), dim3(256), 0, stream, wsd);
    hipLaunchKernelGGL(conv_all, dim3(1024), dim3(256), 0, stream,
                       w_ih0_1, w_ihr_1, w_hh_1, w_ih0_2, w_ihr_2, w_hh_2, wsd);
    hipLaunchKernelGGL(conv_x, dim3(256), dim3(256), 0, stream, x, wsd);
    hipLaunchKernelGGL(lstm_persist, dim3(512), dim3(512), 0, stream,
                       b_1, b_2, wsd, out);
}

// Round 14
// 2997.697 us; speedup vs baseline: 1.7401x; 1.7401x over previous
//
#include <hip/hip_runtime.h>
#include <math.h>

typedef unsigned short u16;
typedef unsigned int   u32;
typedef unsigned long long u64;
typedef __bf16 bf16x8 __attribute__((ext_vector_type(8)));
typedef float  f32x4  __attribute__((ext_vector_type(4)));

#define BB 256
#define TT 256
#define HD 256
#define ED 128
#define DEPTH 4      /* h ring slots (must exceed epoch span S=2) */
#define NE 137       /* epochs: 128 + 9 */

/* ws layout (u32 units):
   [0, H_U32)        : h ring, packed bf16 hi|lo<<16  [10][DEPTH][256][256]
   [CTR_OFF, +512)   : 8 barrier counters (128B padded) + gen broadcast @+256
   [GRP_OFF, +640)   : 20 group counters (l*2+bt), 128B padded
   [XP_OFF, +XP_U32) : packed x  [256][256][8]
   [WT_OFF, ...)     : fragment-ordered bf16 weights (r4-r10 proven layout) */
#define H_U32   (10 * DEPTH * BB * HD)
#define CTR_OFF H_U32
#define GRP_OFF (CTR_OFF + 512)
#define XP_OFF  (GRP_OFF + 640)
#define XP_U32  (BB * TT * 8)
#define WT_OFF  (XP_OFF + XP_U32)

__constant__ size_t g_woff[10] = {0ul,589824ul,1638400ul,2686976ul,3735552ul,
                                  4784128ul,5177344ul,5439488ul,5701632ul,5963776ul};
__constant__ int g_cb[11] = {0,73728,204800,335872,466944,598016,
                             647168,679936,712704,745472,778240};

__device__ __forceinline__ u16 f2bf_hi(float f) {
    u32 u = __float_as_uint(f);
    u32 r = (u + 0x7FFFu + ((u >> 16) & 1u)) >> 16;
    return (u16)r;
}
__device__ __forceinline__ float bf2f(u16 h) { return __uint_as_float(((u32)h) << 16); }
__device__ __forceinline__ float sigmoidf_(float v) { return 1.0f / (1.0f + expf(-v)); }

__global__ __launch_bounds__(256) void zero_state(u32* wsd) {
    const int n = XP_OFF;
    for (int i = blockIdx.x * blockDim.x + threadIdx.x; i < n; i += gridDim.x * blockDim.x)
        wsd[i] = 0u;
}

__global__ __launch_bounds__(256) void conv_x(const float* __restrict__ x, u32* __restrict__ wsd) {
    u32* xp = wsd + XP_OFF;
    for (int i = blockIdx.x * blockDim.x + threadIdx.x; i < XP_U32; i += gridDim.x * blockDim.x) {
        float v = x[i];
        u16 hi = f2bf_hi(v);
        u16 lo = f2bf_hi(v - bf2f(hi));
        xp[i] = (u32)hi | ((u32)lo << 16);
    }
}

/* weights -> bf16 hi/lo, MFMA fragment order (identical to rounds 4-10) */
__global__ __launch_bounds__(256) void conv_all(
    const float* __restrict__ w_ih0_1, const float* __restrict__ w_ihr_1,
    const float* __restrict__ w_hh_1,
    const float* __restrict__ w_ih0_2, const float* __restrict__ w_ihr_2,
    const float* __restrict__ w_hh_2,
    u32* __restrict__ wsd)
{
    __bf16* dst0 = (__bf16*)(wsd + WT_OFF);
    const int nch = 778240;
    for (int ci = blockIdx.x * blockDim.x + threadIdx.x; ci < nch;
         ci += gridDim.x * blockDim.x) {
        int l = 0;
        while (ci >= g_cb[l + 1]) ++l;
        int di = ci - g_cb[l];

        const int hd  = (l < 5) ? 256 : 128;
        const int din = (l == 0) ? 32 : ((l < 6) ? 256 : 128);
        const int xw  = (l == 0) ? 8 : din;
        const int Kp  = din + hd;
        const int nk  = Kp >> 5;

        const float *wih, *whh; int wihld, whhld;
        if (l == 0)      { wih = w_ih0_1;                                whh = w_hh_1;
                           wihld = 8;   whhld = 256; }
        else if (l < 5)  { wih = w_ihr_1 + (size_t)(l - 1) * 1024 * 256; whh = w_hh_1 + (size_t)l * 1024 * 256;
                           wihld = 256; whhld = 256; }
        else if (l == 5) { wih = w_ih0_2;                                whh = w_hh_2;
                           wihld = 256; whhld = 128; }
        else             { wih = w_ihr_2 + (size_t)(l - 6) * 512 * 128;  whh = w_hh_2 + (size_t)(l - 5) * 512 * 128;
                           wihld = 128; whhld = 128; }

        int lane = di & 63;
        int rem  = di >> 6;
        int kt   = rem % nk;
        int rem2 = rem / nk;
        int p    = rem2 & 1;
        int g    = (rem2 >> 1) & 3;
        int jt   = rem2 >> 3;
        int r15  = lane & 15, kq = lane >> 4;
        int row  = g * hd + jt * 16 + r15;

        bf16x8 o8;
        #pragma unroll
        for (int e = 0; e < 8; ++e) {
            int k = kt * 32 + kq * 8 + e;
            float v = 0.0f;
            if (k < xw) v = wih[(size_t)row * wihld + k];
            else if (k >= din && k < Kp) v = whh[(size_t)row * whhld + (k - din)];
            __bf16 h = (__bf16)v;
            o8[e] = p ? (__bf16)(v - (float)h) : h;
        }
        *(bf16x8*)(dst0 + g_woff[l] + (size_t)di * 8) = o8;
    }
}

__device__ __forceinline__ void unpack8(const uint4& a, const uint4& b, bf16x8& bh, bf16x8& bl) {
    union { u32 u[4]; bf16x8 v; } H, L;
    H.u[0] = (a.x & 0xFFFFu) | (a.y << 16);
    H.u[1] = (a.z & 0xFFFFu) | (a.w << 16);
    H.u[2] = (b.x & 0xFFFFu) | (b.y << 16);
    H.u[3] = (b.z & 0xFFFFu) | (b.w << 16);
    L.u[0] = (a.x >> 16) | (a.y & 0xFFFF0000u);
    L.u[1] = (a.z >> 16) | (a.w & 0xFFFF0000u);
    L.u[2] = (b.x >> 16) | (b.y & 0xFFFF0000u);
    L.u[3] = (b.z >> 16) | (b.w & 0xFFFF0000u);
    bh = H.v; bl = L.v;
}

/* persistent epoch loop (S=2): even step after global barrier; odd step after
   cheap per-(l,bt) group sync. Step body identical to round 10. */
template<int NKI, int NKT, bool ISL0>
__device__ void run_persist(int l, int bid, int xcd, int jt, int bt, int hd, u32 arr7,
    int nblkg, u32* __restrict__ gflg,
    const float* __restrict__ bias, u32* __restrict__ hbuf, u32* __restrict__ ctr,
    const u32* __restrict__ xp, float* __restrict__ out, const u16* __restrict__ A_sh)
{
    constexpr int DIN = NKI * 32;
    constexpr int RS  = (NKT < 4) ? NKT : 4;

    const int tid  = threadIdx.x;
    const int lane = tid & 63;
    const int wv   = tid >> 6;
    const int r15  = lane & 15;
    const int kqc  = lane >> 4;
    const int brow = bt * 128 + wv * 16 + r15;
    const int j0   = jt * 16 + kqc * 4;

    float bgr[4][4];
    #pragma unroll
    for (int g = 0; g < 4; ++g) {
        float4 v = *(const float4*)&bias[g * hd + j0];
        bgr[g][0] = v.x; bgr[g][1] = v.y; bgr[g][2] = v.z; bgr[g][3] = v.w;
    }

    int offH[4], offL[4];
    #pragma unroll
    for (int g = 0; g < 4; ++g) {
        offH[g] = (g * 2)     * NKT * 512 + lane * 8;
        offL[g] = (g * 2 + 1) * NKT * 512 + lane * 8;
    }

    float4 cv = make_float4(0.f, 0.f, 0.f, 0.f);
    const int lm = (l > 0) ? (l - 1) : 0;

    auto STEP = [&](int t) {
        const u32* hin   = hbuf + ((size_t)lm * DEPTH + (t & 3)) * (BB * HD);
        const u32* hprev = hbuf + ((size_t)l * DEPTH + ((t - 1) & 3)) * (BB * HD);
        u32*       hout  = hbuf + ((size_t)l * DEPTH + (t & 3)) * (BB * HD);

        auto ldB = [&](int kt, uint4& A, uint4& B) {
            if constexpr (ISL0) {
                if (kt == 0) {
                    if (kqc == 0) {
                        const uint4* p = (const uint4*)(xp + ((size_t)brow * TT + t) * 8);
                        A = p[0]; B = p[1];
                    } else { A = make_uint4(0,0,0,0); B = make_uint4(0,0,0,0); }
                } else {
                    const u32* p = hprev + (size_t)brow * HD + (kt * 32 - 32) + kqc * 8;
                    A = *(const uint4*)p; B = *(const uint4*)(p + 4);
                }
            } else {
                const int k0 = kt * 32 + kqc * 8;
                const u32* p = (k0 < DIN) ? (hin + (size_t)brow * HD + k0)
                                          : (hprev + (size_t)brow * HD + (k0 - DIN));
                A = *(const uint4*)p; B = *(const uint4*)(p + 4);
            }
        };

        f32x4 acc0 = {0.f,0.f,0.f,0.f}, acc1 = {0.f,0.f,0.f,0.f};
        f32x4 acc2 = {0.f,0.f,0.f,0.f}, acc3 = {0.f,0.f,0.f,0.f};

        uint4 ra[RS], rb[RS];
        #pragma unroll
        for (int i = 0; i < RS; ++i) ldB(i, ra[i], rb[i]);

        #pragma unroll
        for (int kt = 0; kt < NKT; ++kt) {
            bf16x8 bh, bl;
            unpack8(ra[kt % RS], rb[kt % RS], bh, bl);
            if (kt + RS < NKT) ldB(kt + RS, ra[kt % RS], rb[kt % RS]);

            const int kof = kt * 512;
            bf16x8 a0h = *(const bf16x8*)&A_sh[offH[0] + kof];
            bf16x8 a1h = *(const bf16x8*)&A_sh[offH[1] + kof];
            bf16x8 a2h = *(const bf16x8*)&A_sh[offH[2] + kof];
            bf16x8 a3h = *(const bf16x8*)&A_sh[offH[3] + kof];
            bf16x8 a0l = *(const bf16x8*)&A_sh[offL[0] + kof];
            bf16x8 a1l = *(const bf16x8*)&A_sh[offL[1] + kof];
            bf16x8 a2l = *(const bf16x8*)&A_sh[offL[2] + kof];
            bf16x8 a3l = *(const bf16x8*)&A_sh[offL[3] + kof];

            acc0 = __builtin_amdgcn_mfma_f32_16x16x32_bf16(a0h, bh, acc0, 0, 0, 0);
            acc1 = __builtin_amdgcn_mfma_f32_16x16x32_bf16(a1h, bh, acc1, 0, 0, 0);
            acc2 = __builtin_amdgcn_mfma_f32_16x16x32_bf16(a2h, bh, acc2, 0, 0, 0);
            acc3 = __builtin_amdgcn_mfma_f32_16x16x32_bf16(a3h, bh, acc3, 0, 0, 0);
            acc0 = __builtin_amdgcn_mfma_f32_16x16x32_bf16(a0h, bl, acc0, 0, 0, 0);
            acc1 = __builtin_amdgcn_mfma_f32_16x16x32_bf16(a1h, bl, acc1, 0, 0, 0);
            acc2 = __builtin_amdgcn_mfma_f32_16x16x32_bf16(a2h, bl, acc2, 0, 0, 0);
            acc3 = __builtin_amdgcn_mfma_f32_16x16x32_bf16(a3h, bl, acc3, 0, 0, 0);
            acc0 = __builtin_amdgcn_mfma_f32_16x16x32_bf16(a0l, bh, acc0, 0, 0, 0);
            acc1 = __builtin_amdgcn_mfma_f32_16x16x32_bf16(a1l, bh, acc1, 0, 0, 0);
            acc2 = __builtin_amdgcn_mfma_f32_16x16x32_bf16(a2l, bh, acc2, 0, 0, 0);
            acc3 = __builtin_amdgcn_mfma_f32_16x16x32_bf16(a3l, bh, acc3, 0, 0, 0);
        }

        float4 hv;
        {
            float i_, f_, g_, o_;
            i_ = sigmoidf_(acc0[0] + bgr[0][0]); f_ = sigmoidf_(acc1[0] + bgr[1][0]);
            g_ = tanhf   (acc2[0] + bgr[2][0]); o_ = sigmoidf_(acc3[0] + bgr[3][0]);
            cv.x = fmaf(f_, cv.x, i_ * g_); hv.x = o_ * tanhf(cv.x);
            i_ = sigmoidf_(acc0[1] + bgr[0][1]); f_ = sigmoidf_(acc1[1] + bgr[1][1]);
            g_ = tanhf   (acc2[1] + bgr[2][1]); o_ = sigmoidf_(acc3[1] + bgr[3][1]);
            cv.y = fmaf(f_, cv.y, i_ * g_); hv.y = o_ * tanhf(cv.y);
            i_ = sigmoidf_(acc0[2] + bgr[0][2]); f_ = sigmoidf_(acc1[2] + bgr[1][2]);
            g_ = tanhf   (acc2[2] + bgr[2][2]); o_ = sigmoidf_(acc3[2] + bgr[3][2]);
            cv.z = fmaf(f_, cv.z, i_ * g_); hv.z = o_ * tanhf(cv.z);
            i_ = sigmoidf_(acc0[3] + bgr[0][3]); f_ = sigmoidf_(acc1[3] + bgr[1][3]);
            g_ = tanhf   (acc2[3] + bgr[2][3]); o_ = sigmoidf_(acc3[3] + bgr[3][3]);
            cv.w = fmaf(f_, cv.w, i_ * g_); hv.w = o_ * tanhf(cv.w);
        }

        u32 pk0, pk1, pk2, pk3;
        {
            u16 h0 = f2bf_hi(hv.x); pk0 = (u32)h0 | ((u32)f2bf_hi(hv.x - bf2f(h0)) << 16);
            u16 h1 = f2bf_hi(hv.y); pk1 = (u32)h1 | ((u32)f2bf_hi(hv.y - bf2f(h1)) << 16);
            u16 h2 = f2bf_hi(hv.z); pk2 = (u32)h2 | ((u32)f2bf_hi(hv.z - bf2f(h2)) << 16);
            u16 h3 = f2bf_hi(hv.w); pk3 = (u32)h3 | ((u32)f2bf_hi(hv.w - bf2f(h3)) << 16);
        }
        u64* hp = (u64*)(hout + (size_t)brow * HD + j0);
        __hip_atomic_store(hp + 0, (u64)pk0 | ((u64)pk1 << 32), __ATOMIC_RELAXED, __HIP_MEMORY_SCOPE_AGENT);
        __hip_atomic_store(hp + 1, (u64)pk2 | ((u64)pk3 << 32), __ATOMIC_RELAXED, __HIP_MEMORY_SCOPE_AGENT);

        if (l == 9 && t == TT - 1)
            *(float4*)&out[(size_t)brow * ED + j0] = hv;
    };

    for (int E = 0; E < NE; ++E) {
        const int t0 = 2 * (E - l);
        /* even step: inputs crossed the last global barrier */
        if (t0 >= 0 && t0 < TT) {
            STEP(t0);
            __syncthreads();   /* drain h stores (vmcnt 0) */
            if (tid == 0)
                __hip_atomic_fetch_add(gflg, 1u, __ATOMIC_RELAXED, __HIP_MEMORY_SCOPE_AGENT);
        }
        /* odd step: own-group recurrent dep -> cheap group sync (no fence) */
        const int t1 = t0 + 1;
        if (t1 >= 1 && t1 < TT) {
            if (tid == 0) {
                const u32 tg = (u32)nblkg * (u32)(E - l + 1);
                for (int it = 0; it < (1 << 20); ++it) {
                    if (__hip_atomic_load(gflg, __ATOMIC_RELAXED,
                                          __HIP_MEMORY_SCOPE_AGENT) >= tg) break;
                    __builtin_amdgcn_s_sleep(1);
                }
            }
            __syncthreads();
            STEP(t1);
        }

        /* ---- global barrier (r10 verbatim): drains stores, aggregates per
           XCD, broadcast gen, acquire-inv fence ---- */
        __syncthreads();
        if (tid == 0) {
            __hip_atomic_fetch_add(&ctr[xcd * 32], 1u,
                                   __ATOMIC_RELAXED, __HIP_MEMORY_SCOPE_AGENT);
            const u32 w1 = (u32)(E + 1);
            if (bid == 0) {
                for (int it = 0; it < (1 << 22); ++it) {
                    bool ok = true;
                    #pragma unroll
                    for (int r = 0; r < 8; ++r) {
                        u32 tgt = ((r == 7) ? arr7 : 32u) * w1;
                        ok &= (__hip_atomic_load(&ctr[r * 32], __ATOMIC_RELAXED,
                                                 __HIP_MEMORY_SCOPE_AGENT) >= tgt);
                    }
                    if (ok) break;
                    __builtin_amdgcn_s_sleep(1);
                }
                __hip_atomic_store(&ctr[256], w1, __ATOMIC_RELAXED, __HIP_MEMORY_SCOPE_AGENT);
            } else {
                for (int it = 0; it < (1 << 22); ++it) {
                    if (__hip_atomic_load(&ctr[256], __ATOMIC_RELAXED,
                                          __HIP_MEMORY_SCOPE_AGENT) >= w1) break;
                    __builtin_amdgcn_s_sleep(1);
                }
            }
            __builtin_amdgcn_fence(__ATOMIC_ACQUIRE, "agent");  /* inv, no writeback */
        }
        __syncthreads();
    }
}

/* Grid 256 (16 idle), 512 thr = 8 waves x 16 batches (r10 structure).
   bid%8 = XCD heuristic (correctness placement-agnostic):
     xcd 0-4 : layer = xcd   (16 jt x 2 bt)
     xcd 5   : layers 5,6 ; xcd 6 : layers 7,8 ; xcd 7 : layer 9 (16 blk) */
__global__ __launch_bounds__(512, 2) void lstm_persist(
    const float* __restrict__ b_1, const float* __restrict__ b_2,
    u32* __restrict__ wsd, float* __restrict__ out)
{
    __shared__ __align__(16) u16 A_sh[65536];   /* 128 KiB */

    const int bid = blockIdx.x;
    const int xcd = bid & 7, slot = bid >> 3;
    int l, jt, bt;
    if (xcd < 5)      { l = xcd;               bt = slot >> 4;        jt = slot & 15; }
    else if (xcd == 5){ l = 5 + (slot >> 4);   bt = (slot >> 3) & 1;  jt = slot & 7; }
    else if (xcd == 6){ l = 7 + (slot >> 4);   bt = (slot >> 3) & 1;  jt = slot & 7; }
    else              { if (slot >= 16) return; l = 9; bt = slot >> 3; jt = slot & 7; }

    const int hd  = (l < 5) ? 256 : 128;
    const int din = (l == 0) ? 32 : ((l < 6) ? 256 : 128);
    const int nk  = (din + hd) >> 5;
    const float* bias = (l < 5) ? (b_1 + l * 1024) : (b_2 + (l - 5) * 512);
    const int nblkg = (l < 5) ? 32 : 16;   /* blocks per (l,bt)?  -> per (l,bt): 16 or 8; counter is per (l,bt) */

    u32* hbuf = wsd;
    u32* ctr  = wsd + CTR_OFF;
    u32* gflg = wsd + GRP_OFF + (size_t)(l * 2 + bt) * 32;
    const u32* xp = wsd + XP_OFF;
    const u16* wt = (const u16*)(wsd + WT_OFF);

    const int ng = (l < 5) ? 16 : 8;   /* blocks in this (l,bt) group */
    (void)nblkg;

    /* one-time: copy this block's fragment-ordered weight slice into LDS */
    {
        const uint4* src = (const uint4*)(wt + g_woff[l] + (size_t)jt * 8 * nk * 512);
        uint4* dst = (uint4*)A_sh;
        const int n4 = nk * 512;
        for (int i = threadIdx.x; i < n4; i += 512) dst[i] = src[i];
    }
    __syncthreads();

    if (l == 0)
        run_persist<1, 9, true >(l, bid, xcd, jt, bt, hd, 16u, ng, gflg, bias, hbuf, ctr, xp, out, A_sh);
    else if (l < 5)
        run_persist<8, 16, false>(l, bid, xcd, jt, bt, hd, 16u, ng, gflg, bias, hbuf, ctr, xp, out, A_sh);
    else if (l == 5)
        run_persist<8, 12, false>(l, bid, xcd, jt, bt, hd, 16u, ng, gflg, bias, hbuf, ctr, xp, out, A_sh);
    else
        run_persist<4, 8, false>(l, bid, xcd, jt, bt, hd, 16u, ng, gflg, bias, hbuf, ctr, xp, out, A_sh);
}

extern "C" void kernel_launch(void* const* d_in, const int* in_sizes, int n_in,
                              void* d_out, int out_size, void* d_ws, size_t ws_size,
                              hipStream_t stream) {
    const float* x       = (const float*)d_in[0];
    const float* w_ih0_1 = (const float*)d_in[1];
    const float* w_ihr_1 = (const float*)d_in[2];
    const float* w_hh_1  = (const float*)d_in[3];
    const float* b_1     = (const float*)d_in[4];
    const float* w_ih0_2 = (const float*)d_in[5];
    const float* w_ihr_2 = (const float*)d_in[6];
    const float* w_hh_2  = (const float*)d_in[7];
    const float* b_2     = (const float*)d_in[8];
    u32*   wsd = (u32*)d_ws;
    float* out = (float*)d_out;

    hipLaunchKernelGGL(zero_state, dim3(1024), dim3(256), 0, stream, wsd);
    hipLaunchKernelGGL(conv_all, dim3(1024), dim3(256), 0, stream,
                       w_ih0_1, w_ihr_1, w_hh_1, w_ih0_2, w_ihr_2, w_hh_2, wsd);
    hipLaunchKernelGGL(conv_x, dim3(256), dim3(256), 0, stream, x, wsd);
    hipLaunchKernelGGL(lstm_persist, dim3(256), dim3(512), 0, stream,
                       b_1, b_2, wsd, out);
}